// Round 1
// baseline (1096.756 us; speedup 1.0000x reference)
//
#include <hip/hip_runtime.h>

// Problem constants
constexpr int B    = 4;
constexpr int C    = 256;   // input channels
constexpr int H    = 64;
constexpr int W    = 64;
constexpr int OCO  = 18;    // offset conv output channels (9 taps * 2)
constexpr int OCH  = 256;   // final output channels
constexpr int HW   = H * W; // 4096

// ---------------------------------------------------------------------------
// Kernel 1: offset = conv3x3(x, w_off), stride 1, pad 1.  One thread per
// output element (b, oc, ho, wo).  x reads coalesced over wo; w reads are
// wave-uniform (same b,oc,ho per 64 lanes).
// ---------------------------------------------------------------------------
__global__ __launch_bounds__(256) void offset_conv_kernel(
    const float* __restrict__ x,
    const float* __restrict__ w_off,
    float* __restrict__ offset)
{
    int idx = blockIdx.x * 256 + threadIdx.x;        // over B*18*64*64
    if (idx >= B * OCO * HW) return;
    int wo = idx & 63;
    int ho = (idx >> 6) & 63;
    int oc = (idx >> 12) % OCO;
    int b  = idx / (OCO * HW);

    const float* xb = x + (size_t)b * C * HW;
    float acc = 0.f;
    for (int c = 0; c < C; ++c) {
        const float* xc = xb + c * HW;
        const float* wc = w_off + ((size_t)oc * C + c) * 9;
        #pragma unroll
        for (int ky = 0; ky < 3; ++ky) {
            int y = ho - 1 + ky;
            if ((unsigned)y < 64u) {
                const float* row = xc + y * 64;
                #pragma unroll
                for (int kx = 0; kx < 3; ++kx) {
                    int xx = wo - 1 + kx;
                    float v = ((unsigned)xx < 64u) ? row[xx] : 0.f;
                    acc = fmaf(v, wc[ky * 3 + kx], acc);
                }
            }
        }
    }
    offset[idx] = acc;
}

// ---------------------------------------------------------------------------
// Kernel 2: wT[k][c][o] = w_def[o][c][k]  (so GEMM weight reads coalesce)
// ---------------------------------------------------------------------------
__global__ __launch_bounds__(256) void transpose_w_kernel(
    const float* __restrict__ w_def,
    float* __restrict__ wT)
{
    int idx = blockIdx.x * 256 + threadIdx.x;        // over 9*256*256
    if (idx >= 9 * C * OCH) return;
    int o = idx & 255;
    int c = (idx >> 8) & 255;
    int k = idx >> 16;
    wT[idx] = w_def[((size_t)o * C + c) * 9 + k];
}

// ---------------------------------------------------------------------------
// Kernel 3: fused bilinear-sample + GEMM.
// One block (256 thr) per (b, ho): computes out[b, 0:256, ho, 0:64].
// Per k-tap: bilinear params live in registers (px == lane), samples staged
// to LDS in two 128-channel chunks (32 KB), then an 8o x 8px register-tiled
// fp32 GEMM over channels.
// ---------------------------------------------------------------------------
__global__ __launch_bounds__(256) void deform_kernel(
    const float* __restrict__ x,
    const float* __restrict__ offset,
    const float* __restrict__ wT,
    float* __restrict__ out)
{
    __shared__ float s_S[128][64];   // 32 KB sample chunk [c_local][px]

    const int tid  = threadIdx.x;
    const int b    = blockIdx.x >> 6;
    const int ho   = blockIdx.x & 63;
    const int lane = tid & 63;       // px for staging
    const int wv   = tid >> 6;       // wave id 0..3
    const int og   = tid >> 3;       // 0..31
    const int pg   = tid & 7;        // 0..7
    const int o0   = og * 8;
    const int p0   = pg * 8;

    const float* xb   = x + (size_t)b * C * HW;
    const float* offb = offset + (size_t)b * OCO * HW + ho * 64;

    float acc[8][8];
    #pragma unroll
    for (int i = 0; i < 8; ++i)
        #pragma unroll
        for (int j = 0; j < 8; ++j) acc[i][j] = 0.f;

    #pragma unroll 1
    for (int k = 0; k < 9; ++k) {
        // --- bilinear params for (k, px=lane), kept in registers ---
        int ky = k / 3, kx = k - ky * 3;
        float offy = offb[(2 * k) * HW + lane];
        float offx = offb[(2 * k + 1) * HW + lane];
        float py  = offy + (float)(ho - 1 + ky);
        float pxx = offx + (float)(lane - 1 + kx);
        float y0f = floorf(py), x0f = floorf(pxx);
        float wy1 = py - y0f, wx1 = pxx - x0f;
        float wy0 = 1.f - wy1, wx0 = 1.f - wx1;
        int y0 = (int)y0f, x0 = (int)x0f;
        int y1 = y0 + 1, x1 = x0 + 1;
        float vy0 = ((unsigned)y0 < 64u) ? 1.f : 0.f;
        float vy1 = ((unsigned)y1 < 64u) ? 1.f : 0.f;
        float vx0 = ((unsigned)x0 < 64u) ? 1.f : 0.f;
        float vx1 = ((unsigned)x1 < 64u) ? 1.f : 0.f;
        int y0c = min(max(y0, 0), 63), y1c = min(max(y1, 0), 63);
        int x0c = min(max(x0, 0), 63), x1c = min(max(x1, 0), 63);
        int a00 = y0c * 64 + x0c, a01 = y0c * 64 + x1c;
        int a10 = y1c * 64 + x0c, a11 = y1c * 64 + x1c;
        float w00 = wy0 * wx0 * vy0 * vx0;
        float w01 = wy0 * wx1 * vy0 * vx1;
        float w10 = wy1 * wx0 * vy1 * vx0;
        float w11 = wy1 * wx1 * vy1 * vx1;

        #pragma unroll 1
        for (int cc = 0; cc < 2; ++cc) {
            __syncthreads();   // previous chunk's compute done
            // --- stage 128 channels of samples ---
            #pragma unroll 4
            for (int j = 0; j < 32; ++j) {
                int c_local = wv + j * 4;
                const float* xc = xb + (size_t)(cc * 128 + c_local) * HW;
                float v = w00 * xc[a00] + w01 * xc[a01]
                        + w10 * xc[a10] + w11 * xc[a11];
                s_S[c_local][lane] = v;
            }
            __syncthreads();
            // --- register-tiled GEMM over this channel chunk ---
            const float* wk = wT + ((size_t)k * C + cc * 128) * OCH;
            #pragma unroll 2
            for (int ci = 0; ci < 128; ++ci) {
                float4 wA = *(const float4*)(wk + ci * OCH + o0);
                float4 wB = *(const float4*)(wk + ci * OCH + o0 + 4);
                float4 sA = *(const float4*)(&s_S[ci][p0]);
                float4 sB = *(const float4*)(&s_S[ci][p0 + 4]);
                float wr[8] = {wA.x, wA.y, wA.z, wA.w, wB.x, wB.y, wB.z, wB.w};
                float sr[8] = {sA.x, sA.y, sA.z, sA.w, sB.x, sB.y, sB.z, sB.w};
                #pragma unroll
                for (int i = 0; i < 8; ++i)
                    #pragma unroll
                    for (int j = 0; j < 8; ++j)
                        acc[i][j] = fmaf(wr[i], sr[j], acc[i][j]);
            }
        }
    }

    // --- epilogue: out[b][o0+i][ho][p0..p0+7] ---
    #pragma unroll
    for (int i = 0; i < 8; ++i) {
        float* op = out + ((size_t)(b * OCH + o0 + i) * 64 + ho) * 64 + p0;
        *(float4*)op       = make_float4(acc[i][0], acc[i][1], acc[i][2], acc[i][3]);
        *(float4*)(op + 4) = make_float4(acc[i][4], acc[i][5], acc[i][6], acc[i][7]);
    }
}

// ---------------------------------------------------------------------------
extern "C" void kernel_launch(void* const* d_in, const int* in_sizes, int n_in,
                              void* d_out, int out_size, void* d_ws, size_t ws_size,
                              hipStream_t stream)
{
    const float* x     = (const float*)d_in[0];
    const float* w_off = (const float*)d_in[1];
    const float* w_def = (const float*)d_in[2];
    float* out = (float*)d_out;

    // workspace layout: [offset: 4*18*4096 floats][wT: 9*256*256 floats]
    float* offset = (float*)d_ws;
    float* wT     = offset + (size_t)B * OCO * HW;

    offset_conv_kernel<<<(B * OCO * HW + 255) / 256, 256, 0, stream>>>(x, w_off, offset);
    transpose_w_kernel<<<(9 * C * OCH + 255) / 256, 256, 0, stream>>>(w_def, wT);
    deform_kernel<<<B * H, 256, 0, stream>>>(x, offset, wT, out);
}

// Round 2
// 235.181 us; speedup vs baseline: 4.6635x; 4.6635x over previous
//
#include <hip/hip_runtime.h>

typedef __attribute__((ext_vector_type(8))) short short8;
typedef __attribute__((ext_vector_type(4))) float f32x4;

constexpr int B   = 4;
constexpr int C   = 256;
constexpr int H   = 64;
constexpr int W   = 64;
constexpr int HW  = H * W;          // 4096
constexpr int OCO = 18;             // offset channels
constexpr int KT  = 9 * C;          // 2304, K order: k_idx = tap*256 + c
constexpr int NSTEP = KT / 32;      // 72 K-steps of 32
constexpr int NOFF  = B * OCO * HW; // 294912

__device__ __forceinline__ unsigned short f2bf(float f) {
    unsigned u = __float_as_uint(f);
    u += 0x7FFF + ((u >> 16) & 1);      // RNE
    return (unsigned short)(u >> 16);
}

// ---------------------------------------------------------------------------
// K1: offset conv partials. One thread per (b,ho,px), split-K over channels
// (4 splits x 64 c). Weights are wave-uniform -> s_load. XCD-swizzled grid.
// ---------------------------------------------------------------------------
__global__ __launch_bounds__(256) void offset_conv_part(
    const float* __restrict__ x, const float* __restrict__ w_off,
    float* __restrict__ part)
{
    int orig = blockIdx.x;
    int r = ((orig & 7) << 5) | (orig >> 3);   // XCD swizzle, 256 blocks
    int b = r >> 6, hg = (r >> 2) & 15, cs = r & 3;
    int tid = threadIdx.x;
    int px = tid & 63, ho = hg * 4 + (tid >> 6);

    // per-tap clamped addresses + validity masks (fixed per thread)
    int   addr[9];
    float msk[9];
    #pragma unroll
    for (int ky = 0; ky < 3; ++ky) {
        int y  = ho - 1 + ky;
        int yc = min(max(y, 0), 63);
        bool yok = ((unsigned)y < 64u);
        #pragma unroll
        for (int kx = 0; kx < 3; ++kx) {
            int xx = px - 1 + kx;
            int xc = min(max(xx, 0), 63);
            addr[ky * 3 + kx] = yc * 64 + xc;
            msk[ky * 3 + kx]  = (yok && ((unsigned)xx < 64u)) ? 1.f : 0.f;
        }
    }

    const float* xb = x + (size_t)b * C * HW;
    float acc[OCO];
    #pragma unroll
    for (int oc = 0; oc < OCO; ++oc) acc[oc] = 0.f;

    int c0 = cs * 64;
    for (int c = c0; c < c0 + 64; ++c) {
        const float* xc = xb + (size_t)c * HW;
        float v[9];
        #pragma unroll
        for (int t = 0; t < 9; ++t) v[t] = xc[addr[t]] * msk[t];
        const float* wb = w_off + c * 9;          // w_off[oc][c][tap]
        #pragma unroll
        for (int oc = 0; oc < OCO; ++oc) {
            #pragma unroll
            for (int t = 0; t < 9; ++t)
                acc[oc] = fmaf(v[t], wb[oc * 2304 + t], acc[oc]);
        }
    }
    float* pp = part + (size_t)cs * NOFF + (size_t)b * OCO * HW + ho * 64 + px;
    #pragma unroll
    for (int oc = 0; oc < OCO; ++oc) pp[oc * HW] = acc[oc];
}

// ---------------------------------------------------------------------------
// K1b: reduce the 4 split partials -> offset
// ---------------------------------------------------------------------------
__global__ __launch_bounds__(256) void offset_reduce(
    const float* __restrict__ part, float* __restrict__ offset)
{
    int idx = blockIdx.x * 256 + threadIdx.x;
    if (idx >= NOFF) return;
    offset[idx] = part[idx] + part[NOFF + idx] + part[2 * NOFF + idx] + part[3 * NOFF + idx];
}

// ---------------------------------------------------------------------------
// K2: pack w_def into bf16 A-fragment order.
// wPack[((t*16 + gt)*64 + lane)*8 + j] = bf16(w_def[o][c][tap])
//   o = gt*16 + (lane&15);  k_idx = t*32 + (lane>>4)*8 + j;
//   tap = k_idx>>8; c = k_idx&255.
// ---------------------------------------------------------------------------
__global__ __launch_bounds__(256) void pack_w(
    const float* __restrict__ w_def, unsigned short* __restrict__ wPack)
{
    int tid = blockIdx.x * 256 + threadIdx.x;     // 72*16*64 = 73728
    if (tid >= NSTEP * 16 * 64) return;
    int lane = tid & 63;
    int o = ((tid >> 6) & 15) * 16 + (lane & 15);
    int kbase = (tid >> 10) * 32 + (lane >> 4) * 8;
    union { unsigned short u[8]; short8 v; } pk;
    #pragma unroll
    for (int j = 0; j < 8; ++j) {
        int kidx = kbase + j;
        int c = kidx & 255, tap = kidx >> 8;
        pk.u[j] = f2bf(w_def[((size_t)o * C + c) * 9 + tap]);
    }
    *(short8*)(wPack + (size_t)tid * 8) = pk.v;
}

// ---------------------------------------------------------------------------
// K3: fused bilinear-sample + bf16 MFMA GEMM.
// Block = 512 thr (8 waves) per (b,ho). Wave wv: o in [wv*32, wv*32+32),
// all 64 px. K-steps of 32 (tap uniform per step, tap = ks>>3).
// LDS S tile [kc(4)][px(64)][j(8)] bf16, double buffered (8 KB total).
// MFMA 16x16x32_bf16 layout assumed:
//   A lane l reg j: A[m=l&15][k=(l>>4)*8+j]
//   B lane l reg j: B[k=(l>>4)*8+j][n=l&15]
//   D lane l reg j: D[row=(l>>4)*4+j][col=l&15]   (m89-verified)
// ---------------------------------------------------------------------------
__global__ __launch_bounds__(512) void deform_mfma(
    const float* __restrict__ x, const float* __restrict__ offset,
    const unsigned short* __restrict__ wPack, float* __restrict__ out)
{
    __shared__ __align__(16) unsigned short sS[2][4][64][8];

    int orig = blockIdx.x;
    int r = ((orig & 7) << 5) | (orig >> 3);   // XCD swizzle, 256 blocks
    int b = r >> 6, ho = r & 63;
    int tid = threadIdx.x;
    int lane = tid & 63, wv = tid >> 6;
    int px = lane;

    const float* xb   = x + (size_t)b * C * HW;
    const float* offb = offset + (size_t)b * OCO * HW + ho * 64;

    f32x4 acc[2][4];
    #pragma unroll
    for (int i = 0; i < 2; ++i)
        #pragma unroll
        for (int j = 0; j < 4; ++j) acc[i][j] = (f32x4){0.f, 0.f, 0.f, 0.f};

    float w00 = 0.f, w01 = 0.f, w10 = 0.f, w11 = 0.f;
    int a00 = 0, a01 = 0, a10 = 0, a11 = 0;
    int ptap = -1;

    auto make_params = [&](int tap) {
        int ky = tap / 3, kx = tap - ky * 3;
        float offy = offb[(2 * tap) * HW + px];
        float offx = offb[(2 * tap + 1) * HW + px];
        float py  = offy + (float)(ho - 1 + ky);
        float pxf = offx + (float)(px - 1 + kx);
        float y0f = floorf(py), x0f = floorf(pxf);
        float wy1 = py - y0f, wx1 = pxf - x0f;
        float wy0 = 1.f - wy1, wx0 = 1.f - wx1;
        int y0 = (int)y0f, x0 = (int)x0f;
        int y1 = y0 + 1, x1 = x0 + 1;
        float vy0 = ((unsigned)y0 < 64u) ? 1.f : 0.f;
        float vy1 = ((unsigned)y1 < 64u) ? 1.f : 0.f;
        float vx0 = ((unsigned)x0 < 64u) ? 1.f : 0.f;
        float vx1 = ((unsigned)x1 < 64u) ? 1.f : 0.f;
        int y0c = min(max(y0, 0), 63), y1c = min(max(y1, 0), 63);
        int x0c = min(max(x0, 0), 63), x1c = min(max(x1, 0), 63);
        a00 = y0c * 64 + x0c; a01 = y0c * 64 + x1c;
        a10 = y1c * 64 + x0c; a11 = y1c * 64 + x1c;
        w00 = wy0 * wx0 * vy0 * vx0; w01 = wy0 * wx1 * vy0 * vx1;
        w10 = wy1 * wx0 * vy1 * vx0; w11 = wy1 * wx1 * vy1 * vx1;
    };

    // stage K-step ks into buffer buf: thread covers kk = wv*4 .. wv*4+3
    auto stage = [&](int ks, int buf) {
        int tap = ks >> 3;
        if (tap != ptap) { make_params(tap); ptap = tap; }
        int c0 = (ks & 7) * 32 + wv * 4;
        const float* xc = xb + (size_t)c0 * HW;
        unsigned short hv[4];
        #pragma unroll
        for (int i = 0; i < 4; ++i) {
            const float* p = xc + (size_t)i * HW;
            float v = w00 * p[a00] + w01 * p[a01] + w10 * p[a10] + w11 * p[a11];
            hv[i] = f2bf(v);
        }
        uint2 w2;
        w2.x = (unsigned)hv[0] | ((unsigned)hv[1] << 16);
        w2.y = (unsigned)hv[2] | ((unsigned)hv[3] << 16);
        *(uint2*)&sS[buf][wv >> 1][lane][(wv & 1) * 4] = w2;
    };

    stage(0, 0);
    __syncthreads();
    int cur = 0;
    for (int ks = 0; ks < NSTEP; ++ks) {
        if (ks + 1 < NSTEP) stage(ks + 1, cur ^ 1);

        // A fragments (packed, lane-coalesced 16B)
        const short8* wp = (const short8*)(wPack + ((size_t)(ks * 16 + wv * 2) * 64 + lane) * 8);
        short8 aF0 = wp[0];
        short8 aF1 = wp[64];

        // B fragments from LDS
        short8 bF[4];
        #pragma unroll
        for (int pt = 0; pt < 4; ++pt)
            bF[pt] = *(const short8*)&sS[cur][lane >> 4][pt * 16 + (lane & 15)][0];

        #pragma unroll
        for (int pt = 0; pt < 4; ++pt) {
            acc[0][pt] = __builtin_amdgcn_mfma_f32_16x16x32_bf16(aF0, bF[pt], acc[0][pt], 0, 0, 0);
            acc[1][pt] = __builtin_amdgcn_mfma_f32_16x16x32_bf16(aF1, bF[pt], acc[1][pt], 0, 0, 0);
        }
        __syncthreads();
        cur ^= 1;
    }

    // epilogue: D[row=(l>>4)*4+j][col=l&15]
    #pragma unroll
    for (int ot = 0; ot < 2; ++ot) {
        int o = wv * 32 + ot * 16 + (lane >> 4) * 4;
        #pragma unroll
        for (int pt = 0; pt < 4; ++pt) {
            int pxx = pt * 16 + (lane & 15);
            #pragma unroll
            for (int j = 0; j < 4; ++j)
                out[(((size_t)b * 256 + (o + j)) * 64 + ho) * 64 + pxx] = acc[ot][pt][j];
        }
    }
}

// ---------------------------------------------------------------------------
extern "C" void kernel_launch(void* const* d_in, const int* in_sizes, int n_in,
                              void* d_out, int out_size, void* d_ws, size_t ws_size,
                              hipStream_t stream)
{
    const float* x     = (const float*)d_in[0];
    const float* w_off = (const float*)d_in[1];
    const float* w_def = (const float*)d_in[2];
    float* out = (float*)d_out;

    // ws layout: part[4*294912 f] | offset[294912 f] | wPack[589824 ushort]
    float* part   = (float*)d_ws;
    float* offset = part + (size_t)4 * NOFF;
    unsigned short* wPack = (unsigned short*)(offset + NOFF);

    offset_conv_part<<<256, 256, 0, stream>>>(x, w_off, part);
    offset_reduce<<<(NOFF + 255) / 256, 256, 0, stream>>>(part, offset);
    pack_w<<<(NSTEP * 16 * 64 + 255) / 256, 256, 0, stream>>>(w_def, wPack);
    deform_mfma<<<256, 512, 0, stream>>>(x, offset, wPack, out);
}